// Round 1
// 373.524 us; speedup vs baseline: 1.1800x; 1.1800x over previous
//
#include <hip/hip_runtime.h>

// NLinear: out[b,n,o] = sum_i x[b,n,i] * w[n,i,o] + bias[n,o]
// B=4096, N=200, D_IN=D_OUT=64.
//
// v2: MFMA with split-bf16 (xh*wh + xh*wl + xl*wh), fp32 accumulate.
// Rationale: v1 was LDS-broadcast-bound (16 wave-uniform ds_read_b128 per
// output row ~= 51.2K LDS instrs/CU ~= 205 us). MFMA does the operand
// fan-out in the matrix pipe; x fragments load straight from global
// (32 B contiguous per lane), w staged once per block into LDS and held
// in per-lane registers as B-fragments for the whole block.

#define B_DIM 4096
#define N_DIM 200
#define D 64

typedef __attribute__((ext_vector_type(8))) short bf16x8;   // 8 bf16 = 4 VGPR
typedef __attribute__((ext_vector_type(4))) float f32x4;

__device__ __forceinline__ unsigned bf16_rne(float f) {
  // round-to-nearest-even fp32 -> bf16 (bit trick)
  unsigned u = __float_as_uint(f);
  return (u + 0x7fffu + ((u >> 16) & 1u)) >> 16;
}

__device__ __forceinline__ void cvt_split8(const float4 a, const float4 b,
                                           bf16x8& h, bf16x8& l) {
  float f[8] = {a.x, a.y, a.z, a.w, b.x, b.y, b.z, b.w};
#pragma unroll
  for (int j = 0; j < 8; ++j) {
    const unsigned hb = bf16_rne(f[j]);
    const float r = f[j] - __uint_as_float(hb << 16);
    const unsigned lb = bf16_rne(r);
    h[j] = (short)hb;
    l[j] = (short)lb;
  }
}

__global__ __launch_bounds__(256, 2)
void nlinear_mfma(const float* __restrict__ x,
                  const float* __restrict__ w,
                  const float* __restrict__ bias,
                  float* __restrict__ out) {
  const int n    = blockIdx.y;
  const int tid  = threadIdx.x;
  const int lane = tid & 63;
  const int wave = tid >> 6;
  const int c    = lane & 15;   // A-row / B-col / D-col within fragment
  const int kg   = lane >> 4;   // k-group (0..3)

  __shared__ float w_lds[D * D];   // 16 KB, raw fp32 w[n][i][o]
  __shared__ float b_lds[D];

  // Cooperative coalesced load of w[n] (4096 floats = 1024 float4).
  {
    const float4* src = (const float4*)(w + (size_t)n * (D * D));
    float4* dst = (float4*)w_lds;
#pragma unroll
    for (int k = 0; k < 4; ++k) dst[tid + 256 * k] = src[tid + 256 * k];
    if (tid < 16)
      ((float4*)b_lds)[tid] = ((const float4*)(bias + (size_t)n * D))[tid];
  }
  __syncthreads();

  // Persistent per-lane B fragments: B[k][col], col = nf*16 + c,
  // k = ks*32 + kg*8 + j  (same k-map as the A side -> layout-consistent).
  bf16x8 Wh[2][4], Wl[2][4];
#pragma unroll
  for (int ks = 0; ks < 2; ++ks) {
#pragma unroll
    for (int nf = 0; nf < 4; ++nf) {
#pragma unroll
      for (int j = 0; j < 8; ++j) {
        const int i = ks * 32 + kg * 8 + j;
        const float v = w_lds[i * D + nf * 16 + c];
        const unsigned hb = bf16_rne(v);
        const float r = v - __uint_as_float(hb << 16);
        const unsigned lb = bf16_rne(r);
        Wh[ks][nf][j] = (short)hb;
        Wl[ks][nf][j] = (short)lb;
      }
    }
  }

  const size_t rstride = (size_t)N_DIM * D;       // 12800 floats per b-row
  const int row0 = blockIdx.x * 256 + wave * 64;  // this wave's 64 rows
  const float* xb = x + (size_t)row0 * rstride + (size_t)n * D;
  float* ob = out + (size_t)row0 * rstride + (size_t)n * D;

  const float bv[4] = {b_lds[c], b_lds[16 + c], b_lds[32 + c], b_lds[48 + c]};

#pragma unroll
  for (int mf = 0; mf < 4; ++mf) {
    // A fragment: row = mf*16 + c, k = ks*32 + kg*8 + j -> 2x 16B + 2x 16B
    const float* xr = xb + (size_t)(mf * 16 + c) * rstride + kg * 8;
    const float4 v0 = *(const float4*)(xr);
    const float4 v1 = *(const float4*)(xr + 4);
    const float4 v2 = *(const float4*)(xr + 32);
    const float4 v3 = *(const float4*)(xr + 36);
    bf16x8 ah[2], al[2];
    cvt_split8(v0, v1, ah[0], al[0]);
    cvt_split8(v2, v3, ah[1], al[1]);

    f32x4 acc[4];
#pragma unroll
    for (int nf = 0; nf < 4; ++nf) {
      f32x4 t = {bv[nf], bv[nf], bv[nf], bv[nf]};
      acc[nf] = t;
    }

#pragma unroll
    for (int ks = 0; ks < 2; ++ks) {
#pragma unroll
      for (int nf = 0; nf < 4; ++nf) {
        acc[nf] = __builtin_amdgcn_mfma_f32_16x16x32_bf16(ah[ks], Wh[ks][nf], acc[nf], 0, 0, 0);
        acc[nf] = __builtin_amdgcn_mfma_f32_16x16x32_bf16(ah[ks], Wl[ks][nf], acc[nf], 0, 0, 0);
        acc[nf] = __builtin_amdgcn_mfma_f32_16x16x32_bf16(al[ks], Wh[ks][nf], acc[nf], 0, 0, 0);
      }
    }

    // D map (verified): col = lane&15, row = (lane>>4)*4 + j.
    float* orow = ob + (size_t)(mf * 16 + kg * 4) * rstride;
#pragma unroll
    for (int nf = 0; nf < 4; ++nf) {
#pragma unroll
      for (int j = 0; j < 4; ++j) {
        orow[(size_t)j * rstride + nf * 16 + c] = acc[nf][j];
      }
    }
  }
}

extern "C" void kernel_launch(void* const* d_in, const int* in_sizes, int n_in,
                              void* d_out, int out_size, void* d_ws, size_t ws_size,
                              hipStream_t stream) {
  const float* x    = (const float*)d_in[0];   // (4096, 200, 64)
  const float* w    = (const float*)d_in[1];   // (1, 200, 64, 64)
  const float* bias = (const float*)d_in[2];   // (1, 200, 64)
  float*       out  = (float*)d_out;           // (4096, 200, 64)

  dim3 grid(B_DIM / 256, N_DIM);   // 16 x 200 blocks, 256 rows per block
  nlinear_mfma<<<grid, dim3(256), 0, stream>>>(x, w, bias, out);
}